// Round 3
// baseline (290.677 us; speedup 1.0000x reference)
//
#include <hip/hip_runtime.h>
#include <hip/hip_bf16.h>
#include <stdint.h>

#define NQ 4096
#define NK 128
#define DIM 256

typedef __attribute__((ext_vector_type(4))) float f32x4;
typedef __attribute__((ext_vector_type(8))) __bf16 bf16x8;
typedef __attribute__((ext_vector_type(8))) unsigned short ushort8;

__device__ __forceinline__ unsigned short f2bf(float x) {
    union { float f; unsigned u; } v; v.f = x;
    unsigned r = v.u + 0x7FFFu + ((v.u >> 16) & 1u);   // round-to-nearest-even
    return (unsigned short)(r >> 16);
}

// ---------------------------------------------------------------------------
// prep 1: pack W_pr1 into bf16 B-fragment-major (verified layout, round 2)
// ---------------------------------------------------------------------------
__global__ void prep_pack(const float* __restrict__ Wpr1, ushort* __restrict__ Bp) {
    int t = blockIdx.x * 256 + threadIdx.x;  // 0..8191
    int lane = t & 63;
    int fid = t >> 6;                        // 0..127
    int h   = fid >> 6;
    int ctl = (fid >> 3) & 7;
    int kt  = fid & 7;
    int e = (h * 8 + ctl) * 16 + (lane & 15);
    int d = kt * 32 + (lane >> 4) * 8;
    const float* src = Wpr1 + (size_t)e * DIM + d;
    ushort* dst = Bp + ((size_t)fid * 64 + lane) * 8;
#pragma unroll
    for (int j = 0; j < 8; j++) dst[j] = f2bf(src[j]);
}

// ---------------------------------------------------------------------------
// prep 2: q_mu / q_lv dots (1 wave per query)
// ---------------------------------------------------------------------------
__global__ void prep_qdots(const float* __restrict__ Q,
                           const float* __restrict__ wmq,
                           const float* __restrict__ wlq,
                           float* __restrict__ qmu, float* __restrict__ qlv) {
    int q = blockIdx.x * 4 + (threadIdx.x >> 6);
    int lane = threadIdx.x & 63;
    const float* Qr = Q + (size_t)q * DIM;
    float dm = 0.f, dl = 0.f;
#pragma unroll
    for (int i = lane; i < DIM; i += 64) {
        float x = Qr[i];
        dm += x * wmq[i];
        dl += x * wlq[i];
    }
#pragma unroll
    for (int s = 32; s; s >>= 1) { dm += __shfl_xor(dm, s); dl += __shfl_xor(dl, s); }
    if (lane == 0) { qmu[q] = dm; qlv[q] = dl; }
}

// ---------------------------------------------------------------------------
// phase macros for the fused kernel (block-parity staggered scheduling)
// ---------------------------------------------------------------------------
#define GEMM_HALF(HOFF)                                                          \
    _Pragma("unroll")                                                            \
    for (int ctl = 0; ctl < 8; ctl++) {                                          \
        f32x4 acc = {0.f, 0.f, 0.f, 0.f};                                        \
        _Pragma("unroll")                                                        \
        for (int kt = 0; kt < 8; kt++) {                                         \
            ushort8 bu = *(const ushort8*)&Blds[((ctl * 8 + kt) * 64 + lane) * 8];\
            acc = __builtin_amdgcn_mfma_f32_16x16x32_bf16(                       \
                afrag[kt], __builtin_bit_cast(bf16x8, bu), acc, 0, 0, 0);        \
        }                                                                        \
        int e = (HOFF) + ctl * 16 + r15;                                         \
        float hb = bp1_s[e], wpv = wp2_s[e];                                     \
        _Pragma("unroll")                                                        \
        for (int rg = 0; rg < 4; rg++) pm[rg] += fmaxf(acc[rg] + hb, 0.f) * wpv; \
    }

#define RESTAGE_B_HALF1                                                          \
    __syncthreads();                                                             \
    {                                                                            \
        const uint4* src = (const uint4*)Bp;                                     \
        uint4* dst = (uint4*)Blds;                                               \
        _Pragma("unroll")                                                        \
        for (int i = 0; i < 8; i++) {                                            \
            int f = w * 8 + i;                                                   \
            dst[f * 64 + lane] = src[(64 + f) * 64 + lane];                      \
        }                                                                        \
    }                                                                            \
    __syncthreads();

#define KL_REDUCE                                                                \
    _Pragma("unroll")                                                            \
    for (int s = 1; s < 16; s <<= 1) {                                           \
        pm[0] += __shfl_xor(pm[0], s); pm[1] += __shfl_xor(pm[1], s);            \
        pm[2] += __shfl_xor(pm[2], s); pm[3] += __shfl_xor(pm[3], s);            \
    }                                                                            \
    {                                                                            \
        float klp = 0.f;                                                         \
        _Pragma("unroll")                                                        \
        for (int rg = 0; rg < 4; rg++) {                                         \
            int rr = w * 16 + g4 * 4 + rg;                                       \
            float mup = pm[rg] + b_pr2 - 0.5f;                                   \
            float dd = mu_s[rr] - mup;                                           \
            klp += -0.5f * lv_s[rr] + 0.5f * (sg_s[rr] * sg_s[rr] + dd * dd) - 0.5f; \
        }                                                                        \
        klp += __shfl_xor(klp, 16); klp += __shfl_xor(klp, 32);                  \
        if (lane == 0) red_s[w] = klp;                                           \
    }

#define V_PHASE                                                                  \
    {                                                                            \
        f32x4 c4 = {0.f, 0.f, 0.f, 0.f};                                        \
        const f32x4* V4 = (const f32x4*)(V + (size_t)q * NK * DIM);              \
        _Pragma("unroll")                                                        \
        for (int kk = 0; kk < 16; kk++) {                                        \
            int k = w * 16 + kk;                                                 \
            float wk = wgt_s[k];                                                 \
            f32x4 v = V4[k * 64 + lane];                                         \
            c4 += v * wk;                                                        \
        }                                                                        \
        if (w >= 4) cpart[(w - 4) * 64 + lane] = c4;                             \
        __syncthreads();                                                         \
        if (w < 4) c4 += cpart[w * 64 + lane];                                   \
        __syncthreads();                                                         \
        if (w == 2 || w == 3) cpart[(w - 2) * 64 + lane] = c4;                   \
        __syncthreads();                                                         \
        if (w < 2) c4 += cpart[w * 64 + lane];                                   \
        __syncthreads();                                                         \
        if (w == 1) cpart[lane] = c4;                                            \
        __syncthreads();                                                         \
        if (w == 0) {                                                            \
            c4 += cpart[lane];                                                   \
            float s1 = c4[0] + c4[1] + c4[2] + c4[3];                            \
            float s2 = c4[0]*c4[0] + c4[1]*c4[1] + c4[2]*c4[2] + c4[3]*c4[3];    \
            _Pragma("unroll")                                                    \
            for (int s = 32; s; s >>= 1) { s1 += __shfl_xor(s1, s); s2 += __shfl_xor(s2, s); } \
            float mean = s1 * (1.f / 256.f);                                     \
            float var = s2 * (1.f / 256.f) - mean * mean;                        \
            float rin = rsqrtf(var + 1e-5f);                                     \
            f32x4 gv = *(const f32x4*)&gam_s[lane * 4];                          \
            f32x4 bv = *(const f32x4*)&bet_s[lane * 4];                          \
            f32x4 o;                                                             \
            _Pragma("unroll")                                                    \
            for (int c = 0; c < 4; c++) o[c] = (c4[c] - mean) * rin * gv[c] + bv[c]; \
            *(f32x4*)(out + (size_t)q * DIM + lane * 4) = o;                     \
        }                                                                        \
    }

// ---------------------------------------------------------------------------
// main fused kernel: block = 1 query, 512 threads (8 waves), 2 blocks/CU.
// Even blocks: GEMM then V-stream. Odd blocks: V-stream then GEMM.
// Anti-phased co-resident pairs keep HBM busy during the other's LDS phase.
// ---------------------------------------------------------------------------
__global__ __launch_bounds__(512, 4) void fused_main(
    const float* __restrict__ K, const float* __restrict__ V,
    const float* __restrict__ eps,
    const float* __restrict__ wmk, const float* __restrict__ bmu_p,
    const float* __restrict__ wlk, const float* __restrict__ blv_p,
    const float* __restrict__ bp1, const float* __restrict__ wp2,
    const float* __restrict__ bp2_p,
    const float* __restrict__ gamma, const float* __restrict__ beta,
    const ushort* __restrict__ Bp,
    const float* __restrict__ qmu, const float* __restrict__ qlv,
    float* __restrict__ klpart, float* __restrict__ out) {

    __shared__ __align__(16) ushort Blds[32768];             // 64 KB (one B half)
    __shared__ __align__(16) float wmk_s[DIM], wlk_s[DIM], wp2_s[DIM];
    __shared__ __align__(16) float bp1_s[DIM], gam_s[DIM], bet_s[DIM];
    __shared__ float smp_s[NK], mu_s[NK], lv_s[NK], sg_s[NK], wgt_s[NK];
    __shared__ f32x4 cpart[256];                             // 4 KB (tree reduce)
    __shared__ float red_s[8];

    const int tid = threadIdx.x;
    const int w = tid >> 6, lane = tid & 63;
    const int q = blockIdx.x;
    const int r15 = lane & 15, g4 = lane >> 4;

    // stage small params into LDS
    if (tid < DIM) { wmk_s[tid] = wmk[tid]; wlk_s[tid] = wlk[tid]; wp2_s[tid] = wp2[tid]; }
    else { int i = tid - DIM; bp1_s[i] = bp1[i]; gam_s[i] = gamma[i]; bet_s[i] = beta[i]; }

    // stage B half 0 (fragment-major -> linear LDS, 16B/lane, conflict-free)
    {
        const uint4* src = (const uint4*)Bp;
        uint4* dst = (uint4*)Blds;
#pragma unroll
        for (int i = 0; i < 8; i++) { int f = w * 8 + i; dst[f * 64 + lane] = src[f * 64 + lane]; }
    }
    __syncthreads();

    // ---- phase A: K row loads -> f32 dots (posterior) + bf16 A-fragments ----
    const int row = w * 16 + r15;                       // key index owned for dots
    const float* Krow = K + ((size_t)q * NK + row) * DIM;
    bf16x8 afrag[8];
    float dm = 0.f, dl = 0.f;
#pragma unroll
    for (int kt = 0; kt < 8; kt++) {
        const int d0 = kt * 32 + g4 * 8;
        float4 x0 = *(const float4*)(Krow + d0);
        float4 x1 = *(const float4*)(Krow + d0 + 4);
        float4 m0 = *(const float4*)(&wmk_s[d0]);
        float4 m1 = *(const float4*)(&wmk_s[d0 + 4]);
        float4 l0 = *(const float4*)(&wlk_s[d0]);
        float4 l1 = *(const float4*)(&wlk_s[d0 + 4]);
        dm += x0.x * m0.x + x0.y * m0.y + x0.z * m0.z + x0.w * m0.w
            + x1.x * m1.x + x1.y * m1.y + x1.z * m1.z + x1.w * m1.w;
        dl += x0.x * l0.x + x0.y * l0.y + x0.z * l0.z + x0.w * l0.w
            + x1.x * l1.x + x1.y * l1.y + x1.z * l1.z + x1.w * l1.w;
        ushort8 u;
        u[0] = f2bf(x0.x); u[1] = f2bf(x0.y); u[2] = f2bf(x0.z); u[3] = f2bf(x0.w);
        u[4] = f2bf(x1.x); u[5] = f2bf(x1.y); u[6] = f2bf(x1.z); u[7] = f2bf(x1.w);
        afrag[kt] = __builtin_bit_cast(bf16x8, u);
    }
    dm += __shfl_xor(dm, 16); dm += __shfl_xor(dm, 32);
    dl += __shfl_xor(dl, 16); dl += __shfl_xor(dl, 32);

    const float b_mu = bmu_p[0], b_lv = blv_p[0], b_pr2 = bp2_p[0];
    {
        const float lv = qlv[q] + dl + b_lv;
        const float sg = expf(0.5f * lv);
        const float mp = qmu[q] + dm + b_mu - 0.5f * sg * sg;
        const float sm = expf(mp + sg * eps[(size_t)q * NK + row]);
        if (g4 == 0) { smp_s[row] = sm; mu_s[row] = mp; lv_s[row] = lv; sg_s[row] = sg; }
    }
    __syncthreads();

    // ---- softmax over the 128 samples (wave 0) ----
    if (w == 0) {
        float s0 = smp_s[lane], s1 = smp_s[64 + lane];
        float mx = fmaxf(s0, s1);
#pragma unroll
        for (int s = 32; s; s >>= 1) mx = fmaxf(mx, __shfl_xor(mx, s));
        float e0 = expf(s0 - mx), e1 = expf(s1 - mx);
        float sm = e0 + e1;
#pragma unroll
        for (int s = 32; s; s >>= 1) sm += __shfl_xor(sm, s);
        float inv = 1.f / sm;
        wgt_s[lane] = e0 * inv; wgt_s[64 + lane] = e1 * inv;
    }

    f32x4 pm = {0.f, 0.f, 0.f, 0.f};   // mu_prior partials, rows (g4*4+rg)

    if ((q & 1) == 0) {
        // ---- even blocks: GEMM first, V-stream last ----
        GEMM_HALF(0)                       // barrier inside RESTAGE separates
        RESTAGE_B_HALF1                    // softmax write from wgt_s reads below
        GEMM_HALF(128)
        KL_REDUCE
        V_PHASE
    } else {
        // ---- odd blocks: V-stream first, GEMM last ----
        __syncthreads();                   // wgt_s ready before all waves read it
        V_PHASE
        GEMM_HALF(0)
        RESTAGE_B_HALF1
        GEMM_HALF(128)
        KL_REDUCE
    }

    __syncthreads();                       // red_s visible to tid 0
    if (tid == 0) {
        klpart[q] = red_s[0] + red_s[1] + red_s[2] + red_s[3]
                  + red_s[4] + red_s[5] + red_s[6] + red_s[7];
    }
}

// ---------------------------------------------------------------------------
// finalize: deterministic reduction of 4096 per-block KL partials
// ---------------------------------------------------------------------------
__global__ void finalize(const float* __restrict__ klpart, float* __restrict__ out) {
    __shared__ float red[4];
    int t = threadIdx.x;  // 256 threads
    float s = 0.f;
    for (int i = t; i < NQ; i += 256) s += klpart[i];
#pragma unroll
    for (int sh = 32; sh; sh >>= 1) s += __shfl_xor(s, sh);
    if ((t & 63) == 0) red[t >> 6] = s;
    __syncthreads();
    if (t == 0) out[(size_t)NQ * DIM] = (red[0] + red[1] + red[2] + red[3]) * (1.f / ((float)NQ * NK));
}

extern "C" void kernel_launch(void* const* d_in, const int* in_sizes, int n_in,
                              void* d_out, int out_size, void* d_ws, size_t ws_size,
                              hipStream_t stream) {
    const float* Q   = (const float*)d_in[0];
    const float* K   = (const float*)d_in[1];
    const float* V   = (const float*)d_in[2];
    const float* eps = (const float*)d_in[3];
    const float* wmq = (const float*)d_in[4];
    const float* wmk = (const float*)d_in[5];
    const float* bmu = (const float*)d_in[6];
    const float* wlq = (const float*)d_in[7];
    const float* wlk = (const float*)d_in[8];
    const float* blv = (const float*)d_in[9];
    const float* Wp1 = (const float*)d_in[10];
    const float* bp1 = (const float*)d_in[11];
    const float* wp2 = (const float*)d_in[12];
    const float* bp2 = (const float*)d_in[13];
    const float* gam = (const float*)d_in[14];
    const float* bet = (const float*)d_in[15];
    float* out = (float*)d_out;

    char* ws = (char*)d_ws;
    float* qmu    = (float*)(ws + 1024);
    float* qlv    = (float*)(ws + 1024 + 16384);
    float* klpart = (float*)(ws + 1024 + 32768);
    ushort* Bp    = (ushort*)(ws + 65536);

    prep_pack<<<32, 256, 0, stream>>>(Wp1, Bp);
    prep_qdots<<<1024, 256, 0, stream>>>(Q, wmq, wlq, qmu, qlv);
    fused_main<<<NQ, 512, 0, stream>>>(K, V, eps, wmk, bmu, wlk, blv, bp1, wp2, bp2,
                                       gam, bet, Bp, qmu, qlv, klpart, out);
    finalize<<<1, 256, 0, stream>>>(klpart, out);
}

// Round 4
// 233.127 us; speedup vs baseline: 1.2469x; 1.2469x over previous
//
#include <hip/hip_runtime.h>
#include <hip/hip_bf16.h>
#include <stdint.h>

#define NQ 4096
#define NK 128
#define DIM 256

typedef __attribute__((ext_vector_type(4))) float f32x4;
typedef __attribute__((ext_vector_type(8))) __bf16 bf16x8;
typedef __attribute__((ext_vector_type(8))) unsigned short ushort8;

__device__ __forceinline__ unsigned short f2bf(float x) {
    union { float f; unsigned u; } v; v.f = x;
    unsigned r = v.u + 0x7FFFu + ((v.u >> 16) & 1u);   // round-to-nearest-even
    return (unsigned short)(r >> 16);
}

// ---------------------------------------------------------------------------
// prep 1: pack W_pr1 into bf16 B-fragment-major (verified layout, round 2)
// ---------------------------------------------------------------------------
__global__ void prep_pack(const float* __restrict__ Wpr1, ushort* __restrict__ Bp) {
    int t = blockIdx.x * 256 + threadIdx.x;  // 0..8191
    int lane = t & 63;
    int fid = t >> 6;                        // 0..127
    int h   = fid >> 6;
    int ctl = (fid >> 3) & 7;
    int kt  = fid & 7;
    int e = (h * 8 + ctl) * 16 + (lane & 15);
    int d = kt * 32 + (lane >> 4) * 8;
    const float* src = Wpr1 + (size_t)e * DIM + d;
    ushort* dst = Bp + ((size_t)fid * 64 + lane) * 8;
#pragma unroll
    for (int j = 0; j < 8; j++) dst[j] = f2bf(src[j]);
}

// ---------------------------------------------------------------------------
// prep 2: q_mu / q_lv dots (1 wave per query)
// ---------------------------------------------------------------------------
__global__ void prep_qdots(const float* __restrict__ Q,
                           const float* __restrict__ wmq,
                           const float* __restrict__ wlq,
                           float* __restrict__ qmu, float* __restrict__ qlv) {
    int q = blockIdx.x * 4 + (threadIdx.x >> 6);
    int lane = threadIdx.x & 63;
    const float* Qr = Q + (size_t)q * DIM;
    float dm = 0.f, dl = 0.f;
#pragma unroll
    for (int i = lane; i < DIM; i += 64) {
        float x = Qr[i];
        dm += x * wmq[i];
        dl += x * wlq[i];
    }
#pragma unroll
    for (int s = 32; s; s >>= 1) { dm += __shfl_xor(dm, s); dl += __shfl_xor(dl, s); }
    if (lane == 0) { qmu[q] = dm; qlv[q] = dl; }
}

#define GEMM_HALF(HOFF)                                                          \
    _Pragma("unroll")                                                            \
    for (int ctl = 0; ctl < 8; ctl++) {                                          \
        f32x4 acc = {0.f, 0.f, 0.f, 0.f};                                        \
        _Pragma("unroll")                                                        \
        for (int kt = 0; kt < 8; kt++) {                                         \
            ushort8 bu = *(const ushort8*)&Blds[((ctl * 8 + kt) * 64 + lane) * 8];\
            acc = __builtin_amdgcn_mfma_f32_16x16x32_bf16(                       \
                afrag[kt], __builtin_bit_cast(bf16x8, bu), acc, 0, 0, 0);        \
        }                                                                        \
        int e = (HOFF) + ctl * 16 + r15;                                         \
        float hb = bp1_s[e], wpv = wp2_s[e];                                     \
        _Pragma("unroll")                                                        \
        for (int rg = 0; rg < 4; rg++) pm[rg] += fmaxf(acc[rg] + hb, 0.f) * wpv; \
    }

// ---------------------------------------------------------------------------
// main fused kernel: block = 1 query, 512 threads (8 waves), 2 blocks/CU.
// V loads are issued into registers BEFORE each GEMM half and consumed after,
// so HBM streams V while the LDS/MFMA pipes grind the prior-MLP GEMM.
// Raw s_barrier (no vmcnt drain) around the B restage keeps them in flight.
// ---------------------------------------------------------------------------
__global__ __launch_bounds__(512, 4) void fused_main(
    const float* __restrict__ K, const float* __restrict__ V,
    const float* __restrict__ eps,
    const float* __restrict__ wmk, const float* __restrict__ bmu_p,
    const float* __restrict__ wlk, const float* __restrict__ blv_p,
    const float* __restrict__ bp1, const float* __restrict__ wp2,
    const float* __restrict__ bp2_p,
    const float* __restrict__ gamma, const float* __restrict__ beta,
    const ushort* __restrict__ Bp,
    const float* __restrict__ qmu, const float* __restrict__ qlv,
    float* __restrict__ klpart, float* __restrict__ out) {

    __shared__ __align__(16) ushort Blds[32768];             // 64 KB (one B half)
    __shared__ __align__(16) float wmk_s[DIM], wlk_s[DIM], wp2_s[DIM];
    __shared__ __align__(16) float bp1_s[DIM], gam_s[DIM], bet_s[DIM];
    __shared__ float smp_s[NK], mu_s[NK], lv_s[NK], sg_s[NK], wgt_s[NK];
    __shared__ f32x4 cpart[256];                             // 4 KB (tree reduce)
    __shared__ float red_s[8];

    const int tid = threadIdx.x;
    const int w = tid >> 6, lane = tid & 63;
    const int q = blockIdx.x;
    const int r15 = lane & 15, g4 = lane >> 4;

    // stage small params into LDS
    if (tid < DIM) { wmk_s[tid] = wmk[tid]; wlk_s[tid] = wlk[tid]; wp2_s[tid] = wp2[tid]; }
    else { int i = tid - DIM; bp1_s[i] = bp1[i]; gam_s[i] = gamma[i]; bet_s[i] = beta[i]; }

    // stage B half 0 (fragment-major -> linear LDS, conflict-free)
    {
        const uint4* src = (const uint4*)Bp;
        uint4* dst = (uint4*)Blds;
#pragma unroll
        for (int i = 0; i < 8; i++) { int f = w * 8 + i; dst[f * 64 + lane] = src[f * 64 + lane]; }
    }
    __syncthreads();

    // ---- phase A: K row loads -> f32 dots (posterior) + bf16 A-fragments ----
    const int row = w * 16 + r15;                       // key index owned for dots
    const float* Krow = K + ((size_t)q * NK + row) * DIM;
    bf16x8 afrag[8];
    float dm = 0.f, dl = 0.f;
#pragma unroll
    for (int kt = 0; kt < 8; kt++) {
        const int d0 = kt * 32 + g4 * 8;
        float4 x0 = *(const float4*)(Krow + d0);
        float4 x1 = *(const float4*)(Krow + d0 + 4);
        float4 m0 = *(const float4*)(&wmk_s[d0]);
        float4 m1 = *(const float4*)(&wmk_s[d0 + 4]);
        float4 l0 = *(const float4*)(&wlk_s[d0]);
        float4 l1 = *(const float4*)(&wlk_s[d0 + 4]);
        dm += x0.x * m0.x + x0.y * m0.y + x0.z * m0.z + x0.w * m0.w
            + x1.x * m1.x + x1.y * m1.y + x1.z * m1.z + x1.w * m1.w;
        dl += x0.x * l0.x + x0.y * l0.y + x0.z * l0.z + x0.w * l0.w
            + x1.x * l1.x + x1.y * l1.y + x1.z * l1.z + x1.w * l1.w;
        ushort8 u;
        u[0] = f2bf(x0.x); u[1] = f2bf(x0.y); u[2] = f2bf(x0.z); u[3] = f2bf(x0.w);
        u[4] = f2bf(x1.x); u[5] = f2bf(x1.y); u[6] = f2bf(x1.z); u[7] = f2bf(x1.w);
        afrag[kt] = __builtin_bit_cast(bf16x8, u);
    }
    dm += __shfl_xor(dm, 16); dm += __shfl_xor(dm, 32);
    dl += __shfl_xor(dl, 16); dl += __shfl_xor(dl, 32);

    const float b_mu = bmu_p[0], b_lv = blv_p[0], b_pr2 = bp2_p[0];
    {
        const float lv = qlv[q] + dl + b_lv;
        const float sg = expf(0.5f * lv);
        const float mp = qmu[q] + dm + b_mu - 0.5f * sg * sg;
        const float sm = expf(mp + sg * eps[(size_t)q * NK + row]);
        if (g4 == 0) { smp_s[row] = sm; mu_s[row] = mp; lv_s[row] = lv; sg_s[row] = sg; }
    }
    __syncthreads();

    // ---- softmax over the 128 samples (wave 0; others proceed) ----
    if (w == 0) {
        float s0 = smp_s[lane], s1 = smp_s[64 + lane];
        float mx = fmaxf(s0, s1);
#pragma unroll
        for (int s = 32; s; s >>= 1) mx = fmaxf(mx, __shfl_xor(mx, s));
        float e0 = expf(s0 - mx), e1 = expf(s1 - mx);
        float sm = e0 + e1;
#pragma unroll
        for (int s = 32; s; s >>= 1) sm += __shfl_xor(sm, s);
        float inv = 1.f / sm;
        wgt_s[lane] = e0 * inv; wgt_s[64 + lane] = e1 * inv;
    }

    const f32x4* V4 = (const f32x4*)(V + (size_t)q * NK * DIM);
    f32x4 pm = {0.f, 0.f, 0.f, 0.f};   // mu_prior partials, rows (g4*4+rg)
    f32x4 c4 = {0.f, 0.f, 0.f, 0.f};   // context partial

    // issue V batch A (keys w*16 .. w*16+7) -> in flight under GEMM half 0
    f32x4 va0 = V4[(w * 16 + 0) * 64 + lane];
    f32x4 va1 = V4[(w * 16 + 1) * 64 + lane];
    f32x4 va2 = V4[(w * 16 + 2) * 64 + lane];
    f32x4 va3 = V4[(w * 16 + 3) * 64 + lane];
    f32x4 va4 = V4[(w * 16 + 4) * 64 + lane];
    f32x4 va5 = V4[(w * 16 + 5) * 64 + lane];
    f32x4 va6 = V4[(w * 16 + 6) * 64 + lane];
    f32x4 va7 = V4[(w * 16 + 7) * 64 + lane];

    GEMM_HALF(0)

    // --- restage B half 1 under raw barriers (no vmcnt drain) ---
    asm volatile("s_waitcnt lgkmcnt(0)" ::: "memory");
    __builtin_amdgcn_s_barrier();
    __builtin_amdgcn_sched_barrier(0);
    {
        const uint4* src = (const uint4*)Bp;
        uint4* dst = (uint4*)Blds;
#pragma unroll
        for (int i = 0; i < 8; i++) { int f = w * 8 + i; dst[f * 64 + lane] = src[(64 + f) * 64 + lane]; }
    }
    asm volatile("s_waitcnt lgkmcnt(0)" ::: "memory");
    __builtin_amdgcn_s_barrier();
    __builtin_amdgcn_sched_barrier(0);

    // consume batch A (wgt_s valid: softmax wave passed the barriers above)
    c4 += va0 * wgt_s[w * 16 + 0];
    c4 += va1 * wgt_s[w * 16 + 1];
    c4 += va2 * wgt_s[w * 16 + 2];
    c4 += va3 * wgt_s[w * 16 + 3];
    c4 += va4 * wgt_s[w * 16 + 4];
    c4 += va5 * wgt_s[w * 16 + 5];
    c4 += va6 * wgt_s[w * 16 + 6];
    c4 += va7 * wgt_s[w * 16 + 7];

    // issue V batch B (keys w*16+8 .. w*16+15) -> in flight under GEMM half 1
    va0 = V4[(w * 16 + 8)  * 64 + lane];
    va1 = V4[(w * 16 + 9)  * 64 + lane];
    va2 = V4[(w * 16 + 10) * 64 + lane];
    va3 = V4[(w * 16 + 11) * 64 + lane];
    va4 = V4[(w * 16 + 12) * 64 + lane];
    va5 = V4[(w * 16 + 13) * 64 + lane];
    va6 = V4[(w * 16 + 14) * 64 + lane];
    va7 = V4[(w * 16 + 15) * 64 + lane];

    GEMM_HALF(128)

    // ---- KL reduce (shuffles only; V batch B still in flight) ----
#pragma unroll
    for (int s = 1; s < 16; s <<= 1) {
        pm[0] += __shfl_xor(pm[0], s); pm[1] += __shfl_xor(pm[1], s);
        pm[2] += __shfl_xor(pm[2], s); pm[3] += __shfl_xor(pm[3], s);
    }
    {
        float klp = 0.f;
#pragma unroll
        for (int rg = 0; rg < 4; rg++) {
            int rr = w * 16 + g4 * 4 + rg;
            float mup = pm[rg] + b_pr2 - 0.5f;
            float dd = mu_s[rr] - mup;
            klp += -0.5f * lv_s[rr] + 0.5f * (sg_s[rr] * sg_s[rr] + dd * dd) - 0.5f;
        }
        klp += __shfl_xor(klp, 16); klp += __shfl_xor(klp, 32);
        if (lane == 0) red_s[w] = klp;
    }

    // consume batch B
    c4 += va0 * wgt_s[w * 16 + 8];
    c4 += va1 * wgt_s[w * 16 + 9];
    c4 += va2 * wgt_s[w * 16 + 10];
    c4 += va3 * wgt_s[w * 16 + 11];
    c4 += va4 * wgt_s[w * 16 + 12];
    c4 += va5 * wgt_s[w * 16 + 13];
    c4 += va6 * wgt_s[w * 16 + 14];
    c4 += va7 * wgt_s[w * 16 + 15];

    // ---- tree-reduce 8 wave partials, LayerNorm, store ----
    if (w >= 4) cpart[(w - 4) * 64 + lane] = c4;
    __syncthreads();
    if (w < 4) c4 += cpart[w * 64 + lane];
    __syncthreads();
    if (w == 2 || w == 3) cpart[(w - 2) * 64 + lane] = c4;
    __syncthreads();
    if (w < 2) c4 += cpart[w * 64 + lane];
    __syncthreads();
    if (w == 1) cpart[lane] = c4;
    __syncthreads();
    if (w == 0) {
        c4 += cpart[lane];
        float s1 = c4[0] + c4[1] + c4[2] + c4[3];
        float s2 = c4[0] * c4[0] + c4[1] * c4[1] + c4[2] * c4[2] + c4[3] * c4[3];
#pragma unroll
        for (int s = 32; s; s >>= 1) { s1 += __shfl_xor(s1, s); s2 += __shfl_xor(s2, s); }
        float mean = s1 * (1.f / 256.f);
        float var = s2 * (1.f / 256.f) - mean * mean;
        float rin = rsqrtf(var + 1e-5f);
        f32x4 gv = *(const f32x4*)&gam_s[lane * 4];
        f32x4 bv = *(const f32x4*)&bet_s[lane * 4];
        f32x4 o;
#pragma unroll
        for (int c = 0; c < 4; c++) o[c] = (c4[c] - mean) * rin * gv[c] + bv[c];
        *(f32x4*)(out + (size_t)q * DIM + lane * 4) = o;
    }
    if (tid == 0) {
        klpart[q] = red_s[0] + red_s[1] + red_s[2] + red_s[3]
                  + red_s[4] + red_s[5] + red_s[6] + red_s[7];
    }
}

// ---------------------------------------------------------------------------
// finalize: deterministic reduction of 4096 per-block KL partials
// ---------------------------------------------------------------------------
__global__ void finalize(const float* __restrict__ klpart, float* __restrict__ out) {
    __shared__ float red[4];
    int t = threadIdx.x;  // 256 threads
    float s = 0.f;
    for (int i = t; i < NQ; i += 256) s += klpart[i];
#pragma unroll
    for (int sh = 32; sh; sh >>= 1) s += __shfl_xor(s, sh);
    if ((t & 63) == 0) red[t >> 6] = s;
    __syncthreads();
    if (t == 0) out[(size_t)NQ * DIM] = (red[0] + red[1] + red[2] + red[3]) * (1.f / ((float)NQ * NK));
}

extern "C" void kernel_launch(void* const* d_in, const int* in_sizes, int n_in,
                              void* d_out, int out_size, void* d_ws, size_t ws_size,
                              hipStream_t stream) {
    const float* Q   = (const float*)d_in[0];
    const float* K   = (const float*)d_in[1];
    const float* V   = (const float*)d_in[2];
    const float* eps = (const float*)d_in[3];
    const float* wmq = (const float*)d_in[4];
    const float* wmk = (const float*)d_in[5];
    const float* bmu = (const float*)d_in[6];
    const float* wlq = (const float*)d_in[7];
    const float* wlk = (const float*)d_in[8];
    const float* blv = (const float*)d_in[9];
    const float* Wp1 = (const float*)d_in[10];
    const float* bp1 = (const float*)d_in[11];
    const float* wp2 = (const float*)d_in[12];
    const float* bp2 = (const float*)d_in[13];
    const float* gam = (const float*)d_in[14];
    const float* bet = (const float*)d_in[15];
    float* out = (float*)d_out;

    char* ws = (char*)d_ws;
    float* qmu    = (float*)(ws + 1024);
    float* qlv    = (float*)(ws + 1024 + 16384);
    float* klpart = (float*)(ws + 1024 + 32768);
    ushort* Bp    = (ushort*)(ws + 65536);

    prep_pack<<<32, 256, 0, stream>>>(Wp1, Bp);
    prep_qdots<<<1024, 256, 0, stream>>>(Q, wmq, wlq, qmu, qlv);
    fused_main<<<NQ, 512, 0, stream>>>(K, V, eps, wmk, bmu, wlk, blv, bp1, wp2, bp2,
                                       gam, bet, Bp, qmu, qlv, klpart, out);
    finalize<<<1, 256, 0, stream>>>(klpart, out);
}